// Round 12
// baseline (314.891 us; speedup 1.0000x reference)
//
#include <hip/hip_runtime.h>

#define NTOT 12288
#define GAL  4096
#define DIM  256
#define NEG_CNT 12276.0f
#define THR 1e-6f

// ws float offsets
#define SQ_OFF    0          // [12288] norms of quantized rows
#define AN_OFF    12288      // [4096]  pass-1 full row sums
#define DNEG_OFF  16384      // [4096]  (fallback path)
#define KS_OFF    20480      // [4096]  (fallback path)
#define KC_OFF    24576      // [4096]  (fallback path)
#define FR_OFF    28672      // [3]     rm_sum, ap_sum, ap_cnt (store path)
#define POSD_OFF  28676      // [4096*12] (fallback path)
#define BF_OFF    81920      // bf16 buffer: 12288*256 ushorts
// u16 dist matrix (store path): bytes
#define DQ_BYTE_OFF  6619136ull                  // = BF end, 16B aligned
#define DQ_BYTES     100663296ull                // 4096*12288*2
#define WS_NEED      (DQ_BYTE_OFF + DQ_BYTES)    // 107,282,432 B
#define DSCALE 1024.0f
#define DINV   (1.0f/1024.0f)

typedef __attribute__((ext_vector_type(8))) short bf16x8;
typedef __attribute__((ext_vector_type(4))) float f32x4;

__device__ __forceinline__ void gld16(void* lds_p, const void* g) {
    __builtin_amdgcn_global_load_lds(
        (const __attribute__((address_space(1))) unsigned int*)g,
        (__attribute__((address_space(3))) unsigned int*)lds_p, 16, 0, 0);
}

__device__ __forceinline__ float bfu_lo(unsigned u) { return __uint_as_float(u << 16); }
__device__ __forceinline__ float bfu_hi(unsigned u) { return __uint_as_float(u & 0xffff0000u); }

// ---- 1. quantize fp32 -> bf16 (RNE) + norms of quantized rows ----
__global__ __launch_bounds__(256) void prep_kernel(const float* __restrict__ in,
                                                   unsigned short* __restrict__ bf,
                                                   float* __restrict__ sq) {
    const int t = threadIdx.x;
    const int w = t >> 6, l = t & 63;
    const int row = blockIdx.x * 4 + w;
    const float4 v = *reinterpret_cast<const float4*>(&in[(size_t)row * DIM + l * 4]);
    const float vv[4] = {v.x, v.y, v.z, v.w};
    unsigned short h[4];
    float s = 0.f;
#pragma unroll
    for (int i = 0; i < 4; ++i) {
        const unsigned u = __float_as_uint(vv[i]);
        const unsigned r = (u + 0x7fffu + ((u >> 16) & 1u)) >> 16;   // RNE
        h[i] = (unsigned short)r;
        const float q = __uint_as_float(r << 16);
        s = fmaf(q, q, s);
    }
    *reinterpret_cast<ushort4*>(&bf[(size_t)row * DIM + l * 4]) =
        make_ushort4(h[0], h[1], h[2], h[3]);
#pragma unroll
    for (int o = 32; o > 0; o >>= 1) s += __shfl_xor(s, o);
    if (l == 0) sq[row] = s;
}

// ---- 2a. STORE-PATH GEMM: R3's proven 128x128/4-wave single-buffer loop.
// Epilogue: row sums -> AN atomics (shfl) + u16 dist tile -> LDS transpose
// staging (XOR swizzled) -> coalesced global stores.
__global__ __launch_bounds__(256) void gemm_store_kernel(const unsigned short* __restrict__ bf,
                                                         const float* __restrict__ ws_ro,
                                                         float* __restrict__ ws,
                                                         unsigned short* __restrict__ dq) {
    __shared__ __align__(16) unsigned short lds[16384];  // 32KB: A 16KB + B 16KB
    const int t = threadIdx.x, l = t & 63, w = t >> 6;
    const int wr = w >> 1, wc = w & 1;
    const int n0 = blockIdx.x * 128;   // probe/column tile
    const int m0 = blockIdx.y * 128;   // gallery row tile

    f32x4 acc[4][4];
#pragma unroll
    for (int fi = 0; fi < 4; ++fi)
#pragma unroll
        for (int fj = 0; fj < 4; ++fj) acc[fi][fj] = (f32x4){0.f, 0.f, 0.f, 0.f};

    for (int kt = 0; kt < 4; ++kt) {
#pragma unroll
        for (int i = 0; i < 4; ++i) {
            const int ci = i * 256 + t;          // 16B chunk 0..1023
            const int row = ci >> 3;             // 0..127
            const int gc = (ci & 7) ^ (row & 7); // pre-swizzled source (rule 21)
            gld16(&lds[ci * 8],
                  &bf[(size_t)(GAL + m0 + row) * DIM + kt * 64 + gc * 8]);
            gld16(&lds[8192 + ci * 8],
                  &bf[(size_t)(n0 + row) * DIM + kt * 64 + gc * 8]);
        }
        __syncthreads();
#pragma unroll
        for (int ks = 0; ks < 2; ++ks) {
            const int g = ks * 4 + (l >> 4);     // k-chunk 0..7
            bf16x8 af[4], bg[4];
#pragma unroll
            for (int f = 0; f < 4; ++f) {
                const int ra = wr * 64 + f * 16 + (l & 15);
                af[f] = *reinterpret_cast<const bf16x8*>(&lds[ra * 64 + ((g ^ (ra & 7)) * 8)]);
                const int rb = wc * 64 + f * 16 + (l & 15);
                bg[f] = *reinterpret_cast<const bf16x8*>(&lds[8192 + rb * 64 + ((g ^ (rb & 7)) * 8)]);
            }
#pragma unroll
            for (int fi = 0; fi < 4; ++fi)
#pragma unroll
                for (int fj = 0; fj < 4; ++fj)
                    acc[fi][fj] = __builtin_amdgcn_mfma_f32_16x16x32_bf16(
                        af[fi], bg[fj], acc[fi][fj], 0, 0, 0);
        }
        __syncthreads();
    }

    // ---- epilogue ----
    const float* sq = ws_ro + SQ_OFF;
    float sqb[4];
#pragma unroll
    for (int fj = 0; fj < 4; ++fj) sqb[fj] = sq[n0 + wc * 64 + fj * 16 + (l & 15)];
    float sqa[4][4];
#pragma unroll
    for (int fi = 0; fi < 4; ++fi)
#pragma unroll
        for (int j = 0; j < 4; ++j)
            sqa[fi][j] = sq[GAL + m0 + wr * 64 + fi * 16 + (l >> 4) * 4 + j];

    // dist -> row sums + u16 LDS tile [128][128] (XOR-swizzled chunks)
    float rs[4][4];
#pragma unroll
    for (int fi = 0; fi < 4; ++fi)
#pragma unroll
        for (int j = 0; j < 4; ++j) {
            const int lr = wr * 64 + fi * 16 + (l >> 4) * 4 + j;
            const int key = (lr & 15) << 3;
            float s = 0.f;
#pragma unroll
            for (int fj = 0; fj < 4; ++fj) {
                const float d2 = fmaf(-2.f, acc[fi][fj][j], sqa[fi][j] + sqb[fj]);
                const float d = sqrtf(fmaxf(d2, 1e-12f));
                s += d;
                const int lc = wc * 64 + fj * 16 + (l & 15);
                lds[lr * 128 + (lc ^ key)] =
                    (unsigned short)__builtin_fminf(fmaf(d, DSCALE, 0.5f), 65535.f);
            }
            rs[fi][j] = s;
        }
    // AN: reduce over 16 lanes sharing (l>>4), atomics (cross-wave/block)
#pragma unroll
    for (int m = 1; m < 16; m <<= 1)
#pragma unroll
        for (int fi = 0; fi < 4; ++fi)
#pragma unroll
            for (int j = 0; j < 4; ++j) rs[fi][j] += __shfl_xor(rs[fi][j], m);
    if ((l & 15) == 0) {
#pragma unroll
        for (int fi = 0; fi < 4; ++fi)
#pragma unroll
            for (int j = 0; j < 4; ++j)
                atomicAdd(&ws[AN_OFF + m0 + wr * 64 + fi * 16 + (l >> 4) * 4 + j], rs[fi][j]);
    }
    __syncthreads();
    // readback + coalesced global store: thread t -> row t>>1, half t&1
    {
        const int lr = t >> 1, h = t & 1;
        const int key = (lr & 15) << 3;
        unsigned short* gp = &dq[(size_t)(m0 + lr) * NTOT + n0 + h * 64];
#pragma unroll
        for (int i = 0; i < 8; ++i) {
            const int phys = (h * 64 + i * 8) ^ key;
            const uint4 v = *reinterpret_cast<const uint4*>(&lds[lr * 128 + phys]);
            *reinterpret_cast<uint4*>(&gp[i * 8]) = v;
        }
    }
}

// ---- 2b. STORE-PATH stream: one wave per gallery row.
// dneg from AN minus the 12 stored pos entries; ap from those entries;
// unmasked filter over the row; subtract pos leak; rm inline.
__global__ __launch_bounds__(256) void stream_kernel(const unsigned short* __restrict__ dq,
                                                     const float* __restrict__ ws_ro,
                                                     float* __restrict__ ws) {
    const int t = threadIdx.x, l = t & 63, w = t >> 6;
    const int gidx = blockIdx.x * 4 + w;             // gallery row 0..4095
    const unsigned short* row = &dq[(size_t)gidx * NTOT];

    float pd = 0.f, possum = 0.f, aps = 0.f, apc = 0.f;
    if (l < 12) {
        const int pcol = (l >> 2) * 4096 + ((gidx >> 2) << 2) + (l & 3);
        pd = (float)row[pcol] * DINV;
        possum = pd;
        if (pd > 1e-5f) { aps = pd; apc = 1.f; }     // u16==0 encodes clipped diag
    }
#pragma unroll
    for (int m = 1; m < 64; m <<= 1) {
        possum += __shfl_xor(possum, m);
        aps += __shfl_xor(aps, m);
        apc += __shfl_xor(apc, m);
    }
    const float dneg = (ws_ro[AN_OFF + gidx] - possum) * (1.f / NEG_CNT);

    float ks = 0.f, kc = 0.f;
#pragma unroll 4
    for (int it = 0; it < 24; ++it) {
        const uint4 v = *reinterpret_cast<const uint4*>(&row[(it * 64 + l) * 8]);
        const unsigned u[4] = {v.x, v.y, v.z, v.w};
#pragma unroll
        for (int k = 0; k < 4; ++k) {
            const float lo = (float)(u[k] & 0xffffu) * DINV;
            const float hi = (float)(u[k] >> 16) * DINV;
            if (lo > 1e-5f && lo < dneg) { ks += lo; kc += 1.f; }
            if (hi > 1e-5f && hi < dneg) { ks += hi; kc += 1.f; }
        }
    }
    // subtract positives that slipped past the unmasked filter
    float ss = 0.f, sc = 0.f;
    if (l < 12 && pd > 1e-5f && pd < dneg) { ss = pd; sc = 1.f; }
#pragma unroll
    for (int m = 1; m < 64; m <<= 1) {
        ks += __shfl_xor(ks, m); kc += __shfl_xor(kc, m);
        ss += __shfl_xor(ss, m); sc += __shfl_xor(sc, m);
    }
    if (l == 0) {
        atomicAdd(&ws[FR_OFF + 0], (ks - ss) / (kc - sc));
        atomicAdd(&ws[FR_OFF + 1], aps);
        atomicAdd(&ws[FR_OFF + 2], apc);
    }
}

// ---- 2c. STORE-PATH finisher ----
__global__ void out_kernel(const float* __restrict__ ws, float* __restrict__ out) {
    if (threadIdx.x == 0) {
        const float an_mean = ws[FR_OFF + 0] / (float)GAL;
        const float ap_mean = ws[FR_OFF + 1] / ws[FR_OFF + 2];
        out[0] = ap_mean / an_mean;
    }
}

// ================= FALLBACK PATH (current passing R7 code) =================
template <int PASS>
__global__ __launch_bounds__(256) void gemm_kernel(const unsigned short* __restrict__ bf,
                                                   const float* __restrict__ ws_ro,
                                                   float* __restrict__ ws) {
    __shared__ __align__(16) unsigned short lds[32768];
    const int t = threadIdx.x, l = t & 63, w = t >> 6;
    const int wr = w >> 1, wc = w & 1;
    const int n0 = blockIdx.x * 128;
    const int m0 = blockIdx.y * 128;

    f32x4 acc[4][4];
#pragma unroll
    for (int fi = 0; fi < 4; ++fi)
#pragma unroll
        for (int fj = 0; fj < 4; ++fj) acc[fi][fj] = (f32x4){0.f, 0.f, 0.f, 0.f};

    auto stage = [&](int kt, int b) {
#pragma unroll
        for (int i = 0; i < 4; ++i) {
            const int ci = i * 256 + t;
            const int row = ci >> 3;
            const int c = ci & 7;
            const int gc = c ^ (row & 7);
            gld16(&lds[b * 16384 + ci * 8],
                  &bf[(size_t)(GAL + m0 + row) * DIM + kt * 64 + gc * 8]);
            gld16(&lds[b * 16384 + 8192 + ci * 8],
                  &bf[(size_t)(n0 + row) * DIM + kt * 64 + gc * 8]);
        }
    };

    stage(0, 0);
#pragma unroll
    for (int kt = 0; kt < 4; ++kt) {
        if (kt < 3) {
            stage(kt + 1, (kt + 1) & 1);
            asm volatile("s_waitcnt vmcnt(8)" ::: "memory");
        } else {
            asm volatile("s_waitcnt vmcnt(0)" ::: "memory");
        }
        __builtin_amdgcn_s_barrier();
        const unsigned short* A = &lds[(kt & 1) * 16384];
        const unsigned short* B = A + 8192;
#pragma unroll
        for (int ks = 0; ks < 2; ++ks) {
            const int g = ks * 4 + (l >> 4);
            bf16x8 af[4], bg[4];
#pragma unroll
            for (int f = 0; f < 4; ++f) {
                const int ra = wr * 64 + f * 16 + (l & 15);
                af[f] = *reinterpret_cast<const bf16x8*>(&A[ra * 64 + ((g ^ (ra & 7)) * 8)]);
                const int rb = wc * 64 + f * 16 + (l & 15);
                bg[f] = *reinterpret_cast<const bf16x8*>(&B[rb * 64 + ((g ^ (rb & 7)) * 8)]);
            }
#pragma unroll
            for (int fi = 0; fi < 4; ++fi)
#pragma unroll
                for (int fj = 0; fj < 4; ++fj)
                    acc[fi][fj] = __builtin_amdgcn_mfma_f32_16x16x32_bf16(
                        af[fi], bg[fj], acc[fi][fj], 0, 0, 0);
        }
        __builtin_amdgcn_s_barrier();
    }

    const float* sq = ws_ro + SQ_OFF;
    float sqb[4];
#pragma unroll
    for (int fj = 0; fj < 4; ++fj) sqb[fj] = sq[n0 + wc * 64 + fj * 16 + (l & 15)];
    float sqa[4][4];
#pragma unroll
    for (int fi = 0; fi < 4; ++fi)
#pragma unroll
        for (int j = 0; j < 4; ++j)
            sqa[fi][j] = sq[GAL + m0 + wr * 64 + fi * 16 + (l >> 4) * 4 + j];

    float* redA = reinterpret_cast<float*>(&lds[0]);
    float* redB = reinterpret_cast<float*>(&lds[16384]);

    if (PASS == 1) {
        float rs[4][4];
#pragma unroll
        for (int fi = 0; fi < 4; ++fi)
#pragma unroll
            for (int j = 0; j < 4; ++j) {
                float s = 0.f;
#pragma unroll
                for (int fj = 0; fj < 4; ++fj) {
                    const float d2 = fmaf(-2.f, acc[fi][fj][j], sqa[fi][j] + sqb[fj]);
                    s += sqrtf(fmaxf(d2, 1e-12f));
                }
                rs[fi][j] = s;
            }
        __syncthreads();
#pragma unroll
        for (int fi = 0; fi < 4; ++fi)
#pragma unroll
            for (int j = 0; j < 4; ++j) {
                const int lr = wr * 64 + fi * 16 + (l >> 4) * 4 + j;
                redA[lr * 32 + wc * 16 + (l & 15)] = rs[fi][j];
            }
        __syncthreads();
        if (t < 128) {
            float s = 0.f;
#pragma unroll
            for (int c = 0; c < 32; ++c) s += redA[t * 32 + ((c + t) & 31)];
            atomicAdd(&ws[AN_OFF + m0 + t], s);
        }
    } else {
        float dn2[4][4];
#pragma unroll
        for (int fi = 0; fi < 4; ++fi)
#pragma unroll
            for (int j = 0; j < 4; ++j) {
                const float dn = ws_ro[DNEG_OFF + m0 + wr * 64 + fi * 16 + (l >> 4) * 4 + j];
                dn2[fi][j] = dn * dn;
            }
        float ksv[4][4], kcv[4][4];
#pragma unroll
        for (int fi = 0; fi < 4; ++fi)
#pragma unroll
            for (int j = 0; j < 4; ++j) {
                float s = 0.f, c = 0.f;
#pragma unroll
                for (int fj = 0; fj < 4; ++fj) {
                    const float d2 = fmaf(-2.f, acc[fi][fj][j], sqa[fi][j] + sqb[fj]);
                    const float d = sqrtf(fmaxf(d2, 1e-12f));
                    const bool kp = (d2 > 1e-12f) && (d2 < dn2[fi][j]);
                    s += kp ? d : 0.f;
                    c += kp ? 1.f : 0.f;
                }
                ksv[fi][j] = s; kcv[fi][j] = c;
            }
        __syncthreads();
#pragma unroll
        for (int fi = 0; fi < 4; ++fi)
#pragma unroll
            for (int j = 0; j < 4; ++j) {
                const int lr = wr * 64 + fi * 16 + (l >> 4) * 4 + j;
                redA[lr * 32 + wc * 16 + (l & 15)] = ksv[fi][j];
                redB[lr * 32 + wc * 16 + (l & 15)] = kcv[fi][j];
            }
        __syncthreads();
        if (t < 128) {
            float s = 0.f, c = 0.f;
#pragma unroll
            for (int cc = 0; cc < 32; ++cc) {
                const int idx = t * 32 + ((cc + t) & 31);
                s += redA[idx]; c += redB[idx];
            }
            atomicAdd(&ws[KS_OFF + m0 + t], s);
            atomicAdd(&ws[KC_OFF + m0 + t], c);
        }
    }
}

__global__ __launch_bounds__(64) void pos_kernel(const unsigned short* __restrict__ bf,
                                                 float* __restrict__ ws) {
    const int gidx = blockIdx.x;
    const int l = threadIdx.x;
    const int p = l >> 2, q4 = l & 3;
    const int r = GAL + gidx;
    float dot = 0.f;
    int j = 0;
    if (p < 12) {
        const int t3 = p >> 2, q = p & 3;
        j = t3 * 4096 + ((gidx >> 2) << 2) + q;
        const unsigned short* pr = &bf[(size_t)r * DIM + q4 * 64];
        const unsigned short* pc = &bf[(size_t)j * DIM + q4 * 64];
#pragma unroll
        for (int it = 0; it < 8; ++it) {
            const uint4 ua = *reinterpret_cast<const uint4*>(&pr[it * 8]);
            const uint4 ub = *reinterpret_cast<const uint4*>(&pc[it * 8]);
            const unsigned a[4] = {ua.x, ua.y, ua.z, ua.w};
            const unsigned b[4] = {ub.x, ub.y, ub.z, ub.w};
#pragma unroll
            for (int k = 0; k < 4; ++k) {
                dot = fmaf(bfu_lo(a[k]), bfu_lo(b[k]), dot);
                dot = fmaf(bfu_hi(a[k]), bfu_hi(b[k]), dot);
            }
        }
    }
    dot += __shfl_xor(dot, 1);
    dot += __shfl_xor(dot, 2);
    __shared__ float pd[16];
    float dist = 0.f;
    if (q4 == 0) {
        if (p < 12) {
            const float d2 = ws[SQ_OFF + r] + ws[SQ_OFF + j] - 2.f * dot;
            dist = sqrtf(fmaxf(d2, 1e-12f));
            ws[POSD_OFF + gidx * 12 + p] = dist;
        }
        pd[p] = (p < 12) ? dist : 0.f;
    }
    __syncthreads();
    if (l == 0) {
        float s = 0.f;
#pragma unroll
        for (int i = 0; i < 12; ++i) s += pd[i];
        ws[DNEG_OFF + gidx] = (ws[AN_OFF + gidx] - s) * (1.f / NEG_CNT);
    }
}

__global__ __launch_bounds__(1024) void finish_kernel(const float* __restrict__ ws,
                                                      float* __restrict__ out) {
    const int t = threadIdx.x;
    float rm = 0.f, aps = 0.f, apc = 0.f;
#pragma unroll
    for (int it = 0; it < 4; ++it) {
        const int g = it * 1024 + t;
        float ks = ws[KS_OFF + g], kc = ws[KC_OFF + g];
        const float dn = ws[DNEG_OFF + g];
#pragma unroll
        for (int p = 0; p < 12; ++p) {
            const float d = ws[POSD_OFF + g * 12 + p];
            if (d > THR) { aps += d; apc += 1.f; }
            if (d > THR && d < dn) { ks -= d; kc -= 1.f; }
        }
        rm += ks / kc;
    }
#pragma unroll
    for (int o = 1; o < 64; o <<= 1) {
        rm += __shfl_xor(rm, o); aps += __shfl_xor(aps, o); apc += __shfl_xor(apc, o);
    }
    __shared__ float s0[16], s1[16], s2[16];
    const int wv = t >> 6;
    if ((t & 63) == 0) { s0[wv] = rm; s1[wv] = aps; s2[wv] = apc; }
    __syncthreads();
    if (t == 0) {
        float R = 0.f, A = 0.f, C = 0.f;
#pragma unroll
        for (int i = 0; i < 16; ++i) { R += s0[i]; A += s1[i]; C += s2[i]; }
        const float an_mean = R / (float)GAL;
        const float ap_mean = A / C;
        out[0] = ap_mean / an_mean;
    }
}

extern "C" void kernel_launch(void* const* d_in, const int* in_sizes, int n_in,
                              void* d_out, int out_size, void* d_ws, size_t ws_size,
                              hipStream_t stream) {
    const float* in = (const float*)d_in[0];
    float* ws = (float*)d_ws;
    unsigned short* bf = (unsigned short*)(ws + BF_OFF);
    float* out = (float*)d_out;

    // zero accumulated regions (AN .. FR+3)
    hipMemsetAsync((char*)d_ws + AN_OFF * sizeof(float), 0,
                   (FR_OFF + 3 - AN_OFF) * sizeof(float), stream);
    prep_kernel<<<NTOT / 4, 256, 0, stream>>>(in, bf, ws + SQ_OFF);

    if (ws_size >= WS_NEED) {
        // store path: ONE GEMM + L3-resident stream
        unsigned short* dq = (unsigned short*)((char*)d_ws + DQ_BYTE_OFF);
        dim3 grid(NTOT / 128, GAL / 128);
        gemm_store_kernel<<<grid, 256, 0, stream>>>(bf, ws, ws, dq);
        stream_kernel<<<GAL / 4, 256, 0, stream>>>(dq, ws, ws);
        out_kernel<<<1, 64, 0, stream>>>(ws, out);
    } else {
        // fallback: two-pass recompute (R7, passing)
        dim3 grid(NTOT / 128, GAL / 128);
        gemm_kernel<1><<<grid, 256, 0, stream>>>(bf, ws, ws);
        pos_kernel<<<GAL, 64, 0, stream>>>(bf, ws);
        gemm_kernel<2><<<grid, 256, 0, stream>>>(bf, ws, ws);
        finish_kernel<<<1, 1024, 0, stream>>>(ws, out);
    }
}

// Round 13
// 137.134 us; speedup vs baseline: 2.2962x; 2.2962x over previous
//
#include <hip/hip_runtime.h>

#define NTOT 12288
#define GAL  4096
#define DIM  256
#define NEG_CNT 12276.0f
#define THR 1e-6f

// ws float offsets
#define SQ_OFF    0          // [12288] norms of quantized rows
#define AN_OFF    12288      // [4096]  pass-1 full row sums
#define DNEG_OFF  16384      // [4096]  (AN - possum)/12276
#define KS_OFF    20480      // [4096]  pass-2 kept sums (unmasked)
#define KC_OFF    24576      // [4096]  pass-2 kept counts
#define POSD_OFF  28672      // [4096*12] positive-pair dists
#define BF_OFF    81920      // bf16 buffer: 12288*256 ushorts

typedef __attribute__((ext_vector_type(8))) short bf16x8;
typedef __attribute__((ext_vector_type(4))) float f32x4;

__device__ __forceinline__ void gld16(void* lds_p, const void* g) {
    __builtin_amdgcn_global_load_lds(
        (const __attribute__((address_space(1))) unsigned int*)g,
        (__attribute__((address_space(3))) unsigned int*)lds_p, 16, 0, 0);
}

__device__ __forceinline__ float bfu_lo(unsigned u) { return __uint_as_float(u << 16); }
__device__ __forceinline__ float bfu_hi(unsigned u) { return __uint_as_float(u & 0xffff0000u); }

// ---- 1. quantize fp32 -> bf16 (RNE) + norms of quantized rows ----
__global__ __launch_bounds__(256) void prep_kernel(const float* __restrict__ in,
                                                   unsigned short* __restrict__ bf,
                                                   float* __restrict__ sq) {
    const int t = threadIdx.x;
    const int w = t >> 6, l = t & 63;
    const int row = blockIdx.x * 4 + w;
    const float4 v = *reinterpret_cast<const float4*>(&in[(size_t)row * DIM + l * 4]);
    const float vv[4] = {v.x, v.y, v.z, v.w};
    unsigned short h[4];
    float s = 0.f;
#pragma unroll
    for (int i = 0; i < 4; ++i) {
        const unsigned u = __float_as_uint(vv[i]);
        const unsigned r = (u + 0x7fffu + ((u >> 16) & 1u)) >> 16;   // RNE
        h[i] = (unsigned short)r;
        const float q = __uint_as_float(r << 16);
        s = fmaf(q, q, s);
    }
    *reinterpret_cast<ushort4*>(&bf[(size_t)row * DIM + l * 4]) =
        make_ushort4(h[0], h[1], h[2], h[3]);
#pragma unroll
    for (int o = 32; o > 0; o >>= 1) s += __shfl_xor(s, o);
    if (l == 0) sq[row] = s;
}

// ---- 2. MFMA distance GEMM: R3's proven 128x128/4-wave/single-buffer loop,
// with ALL K-loop addressing hoisted out of the loop:
//  - 8 global staging bases (swizzle gc is kt/i-invariant); +kt*64 folds into
//    the 13-bit global offset immediate.
//  - 4 LDS read base indices (ra&7 == (l&15)&7 is f-independent); f*1024 folds
//    into the ds_read offset immediate; ks=1 base = ks=0 base XOR 32 (exact).
// K-loop VALU ~ 0; arithmetic and memory order bit-identical to R3.
template <int PASS>
__global__ __launch_bounds__(256) void gemm_kernel(const unsigned short* __restrict__ bf,
                                                   const float* __restrict__ ws_ro,
                                                   float* __restrict__ ws) {
    __shared__ __align__(16) unsigned short lds[16384];  // 32KB: A 16KB + B 16KB
    const int t = threadIdx.x, l = t & 63, w = t >> 6;
    const int wr = w >> 1, wc = w & 1;
    const int n0 = blockIdx.x * 128;   // probe/column tile
    const int m0 = blockIdx.y * 128;   // gallery row tile

    // ---- hoisted staging addresses ----
    // chunk ci = i*256+t: row = i*32 + (t>>3), colchunk = t&7,
    // swizzled source chunk gc = (t&7) ^ (row&7) = (t&7) ^ ((t>>3)&7)  [i-invariant]
    const int srow = t >> 3;
    const int gc = (t & 7) ^ (srow & 7);
    const unsigned short* gA[4];
    const unsigned short* gB[4];
#pragma unroll
    for (int i = 0; i < 4; ++i) {
        gA[i] = &bf[(size_t)(GAL + m0 + i * 32 + srow) * DIM + gc * 8];
        gB[i] = &bf[(size_t)(n0 + i * 32 + srow) * DIM + gc * 8];
    }

    // ---- hoisted LDS fragment-read bases (ushort indices) ----
    // addr(f,ks) = [wr*4096 + (l&15)*64 + ((g0^s)*8)] + f*1024, s=(l&15)&7, g0=l>>4
    // ks=1: g=g0+4 -> XOR 32 on the index (exact: flips bit 5 of the swizzle field)
    const int s7 = (l & 15) & 7;
    const int iA0 = wr * 4096 + (l & 15) * 64 + (((l >> 4) ^ s7) * 8);
    const int iA1 = iA0 ^ 32;
    const int iB0 = 8192 + wc * 4096 + (l & 15) * 64 + (((l >> 4) ^ s7) * 8);
    const int iB1 = iB0 ^ 32;

    f32x4 acc[4][4];
#pragma unroll
    for (int fi = 0; fi < 4; ++fi)
#pragma unroll
        for (int fj = 0; fj < 4; ++fj) acc[fi][fj] = (f32x4){0.f, 0.f, 0.f, 0.f};

#pragma unroll
    for (int kt = 0; kt < 4; ++kt) {
#pragma unroll
        for (int i = 0; i < 4; ++i) {
            gld16(&lds[(i * 256 + t) * 8], gA[i] + kt * 64);          // offset:kt*128
            gld16(&lds[8192 + (i * 256 + t) * 8], gB[i] + kt * 64);
        }
        __syncthreads();    // drains vmcnt (compiler) -> buffer complete for all waves
#pragma unroll
        for (int ks = 0; ks < 2; ++ks) {
            bf16x8 af[4], bg[4];
#pragma unroll
            for (int f = 0; f < 4; ++f) {
                af[f] = *reinterpret_cast<const bf16x8*>(&lds[(ks ? iA1 : iA0) + f * 1024]);
                bg[f] = *reinterpret_cast<const bf16x8*>(&lds[(ks ? iB1 : iB0) + f * 1024]);
            }
#pragma unroll
            for (int fi = 0; fi < 4; ++fi)
#pragma unroll
                for (int fj = 0; fj < 4; ++fj)
                    acc[fi][fj] = __builtin_amdgcn_mfma_f32_16x16x32_bf16(
                        af[fi], bg[fj], acc[fi][fj], 0, 0, 0);
        }
        __syncthreads();    // reads retired before next stage overwrites
    }

    // ---- R3 epilogue verbatim (LDS reused as float scratch) ----
    const float* sq = ws_ro + SQ_OFF;
    float sqb[4];
#pragma unroll
    for (int fj = 0; fj < 4; ++fj) sqb[fj] = sq[n0 + wc * 64 + fj * 16 + (l & 15)];
    float sqa[4][4];
#pragma unroll
    for (int fi = 0; fi < 4; ++fi)
#pragma unroll
        for (int j = 0; j < 4; ++j)
            sqa[fi][j] = sq[GAL + m0 + wr * 64 + fi * 16 + (l >> 4) * 4 + j];

    float* redA = reinterpret_cast<float*>(&lds[0]);       // [128][32] floats
    float* redB = redA + 4096;                             // [128][32] floats

    if (PASS == 1) {
        float rs[4][4];
#pragma unroll
        for (int fi = 0; fi < 4; ++fi)
#pragma unroll
            for (int j = 0; j < 4; ++j) {
                float s = 0.f;
#pragma unroll
                for (int fj = 0; fj < 4; ++fj) {
                    const float d2 = fmaf(-2.f, acc[fi][fj][j], sqa[fi][j] + sqb[fj]);
                    s += sqrtf(fmaxf(d2, 1e-12f));
                }
                rs[fi][j] = s;
            }
        __syncthreads();
#pragma unroll
        for (int fi = 0; fi < 4; ++fi)
#pragma unroll
            for (int j = 0; j < 4; ++j) {
                const int lr = wr * 64 + fi * 16 + (l >> 4) * 4 + j;
                redA[lr * 32 + wc * 16 + (l & 15)] = rs[fi][j];
            }
        __syncthreads();
        if (t < 128) {
            float s = 0.f;
#pragma unroll
            for (int c = 0; c < 32; ++c) s += redA[t * 32 + ((c + t) & 31)];
            atomicAdd(&ws[AN_OFF + m0 + t], s);
        }
    } else {
        float dn2[4][4];
#pragma unroll
        for (int fi = 0; fi < 4; ++fi)
#pragma unroll
            for (int j = 0; j < 4; ++j) {
                const float dn = ws_ro[DNEG_OFF + m0 + wr * 64 + fi * 16 + (l >> 4) * 4 + j];
                dn2[fi][j] = dn * dn;
            }
        float ksv[4][4], kcv[4][4];
#pragma unroll
        for (int fi = 0; fi < 4; ++fi)
#pragma unroll
            for (int j = 0; j < 4; ++j) {
                float s = 0.f, c = 0.f;
#pragma unroll
                for (int fj = 0; fj < 4; ++fj) {
                    const float d2 = fmaf(-2.f, acc[fi][fj][j], sqa[fi][j] + sqb[fj]);
                    const float d = sqrtf(fmaxf(d2, 1e-12f));
                    const bool kp = (d2 > 1e-12f) && (d2 < dn2[fi][j]);
                    s += kp ? d : 0.f;
                    c += kp ? 1.f : 0.f;
                }
                ksv[fi][j] = s; kcv[fi][j] = c;
            }
        __syncthreads();
#pragma unroll
        for (int fi = 0; fi < 4; ++fi)
#pragma unroll
            for (int j = 0; j < 4; ++j) {
                const int lr = wr * 64 + fi * 16 + (l >> 4) * 4 + j;
                redA[lr * 32 + wc * 16 + (l & 15)] = ksv[fi][j];
                redB[lr * 32 + wc * 16 + (l & 15)] = kcv[fi][j];
            }
        __syncthreads();
        if (t < 128) {
            float s = 0.f, c = 0.f;
#pragma unroll
            for (int cc = 0; cc < 32; ++cc) {
                const int idx = t * 32 + ((cc + t) & 31);
                s += redA[idx]; c += redB[idx];
            }
            atomicAdd(&ws[KS_OFF + m0 + t], s);
            atomicAdd(&ws[KC_OFF + m0 + t], c);
        }
    }
}

// ---- 3. positive pairs (12 per gallery row, known structurally) + dneg ----
// targets[i]==targets[j]  <=>  ((i&4095)>>2)==((j&4095)>>2)
__global__ __launch_bounds__(64) void pos_kernel(const unsigned short* __restrict__ bf,
                                                 float* __restrict__ ws) {
    const int gidx = blockIdx.x;          // gallery row 0..4095
    const int l = threadIdx.x;
    const int p = l >> 2, q4 = l & 3;     // pair index, K-quarter
    const int r = GAL + gidx;
    float dot = 0.f;
    int j = 0;
    if (p < 12) {
        const int t3 = p >> 2, q = p & 3;
        j = t3 * 4096 + ((gidx >> 2) << 2) + q;
        const unsigned short* pr = &bf[(size_t)r * DIM + q4 * 64];
        const unsigned short* pc = &bf[(size_t)j * DIM + q4 * 64];
#pragma unroll
        for (int it = 0; it < 8; ++it) {
            const uint4 ua = *reinterpret_cast<const uint4*>(&pr[it * 8]);
            const uint4 ub = *reinterpret_cast<const uint4*>(&pc[it * 8]);
            const unsigned a[4] = {ua.x, ua.y, ua.z, ua.w};
            const unsigned b[4] = {ub.x, ub.y, ub.z, ub.w};
#pragma unroll
            for (int k = 0; k < 4; ++k) {
                dot = fmaf(bfu_lo(a[k]), bfu_lo(b[k]), dot);
                dot = fmaf(bfu_hi(a[k]), bfu_hi(b[k]), dot);
            }
        }
    }
    dot += __shfl_xor(dot, 1);
    dot += __shfl_xor(dot, 2);
    __shared__ float pd[16];
    float dist = 0.f;
    if (q4 == 0) {
        if (p < 12) {
            const float d2 = ws[SQ_OFF + r] + ws[SQ_OFF + j] - 2.f * dot;
            dist = sqrtf(fmaxf(d2, 1e-12f));
            ws[POSD_OFF + gidx * 12 + p] = dist;
        }
        pd[p] = (p < 12) ? dist : 0.f;
    }
    __syncthreads();
    if (l == 0) {
        float s = 0.f;
#pragma unroll
        for (int i = 0; i < 12; ++i) s += pd[i];
        ws[DNEG_OFF + gidx] = (ws[AN_OFF + gidx] - s) * (1.f / NEG_CNT);
    }
}

// ---- 4. finish: subtract positives that slipped past the unmasked filter,
//         row means, ap mean, output scalar — one block ----
__global__ __launch_bounds__(1024) void finish_kernel(const float* __restrict__ ws,
                                                      float* __restrict__ out) {
    const int t = threadIdx.x;
    float rm = 0.f, aps = 0.f, apc = 0.f;
#pragma unroll
    for (int it = 0; it < 4; ++it) {
        const int g = it * 1024 + t;
        float ks = ws[KS_OFF + g], kc = ws[KC_OFF + g];
        const float dn = ws[DNEG_OFF + g];
#pragma unroll
        for (int p = 0; p < 12; ++p) {
            const float d = ws[POSD_OFF + g * 12 + p];
            if (d > THR) { aps += d; apc += 1.f; }
            if (d > THR && d < dn) { ks -= d; kc -= 1.f; }
        }
        rm += ks / kc;
    }
#pragma unroll
    for (int o = 1; o < 64; o <<= 1) {
        rm += __shfl_xor(rm, o); aps += __shfl_xor(aps, o); apc += __shfl_xor(apc, o);
    }
    __shared__ float s0[16], s1[16], s2[16];
    const int wv = t >> 6;
    if ((t & 63) == 0) { s0[wv] = rm; s1[wv] = aps; s2[wv] = apc; }
    __syncthreads();
    if (t == 0) {
        float R = 0.f, A = 0.f, C = 0.f;
#pragma unroll
        for (int i = 0; i < 16; ++i) { R += s0[i]; A += s1[i]; C += s2[i]; }
        const float an_mean = R / (float)GAL;
        const float ap_mean = A / C;
        out[0] = ap_mean / an_mean;
    }
}

extern "C" void kernel_launch(void* const* d_in, const int* in_sizes, int n_in,
                              void* d_out, int out_size, void* d_ws, size_t ws_size,
                              hipStream_t stream) {
    const float* in = (const float*)d_in[0];
    float* ws = (float*)d_ws;
    unsigned short* bf = (unsigned short*)(ws + BF_OFF);
    float* out = (float*)d_out;

    // zero AN/DNEG/KS/KC (atomically accumulated / derived regions)
    hipMemsetAsync((char*)d_ws + AN_OFF * sizeof(float), 0,
                   (KC_OFF + GAL - AN_OFF) * sizeof(float), stream);
    prep_kernel<<<NTOT / 4, 256, 0, stream>>>(in, bf, ws + SQ_OFF);
    dim3 grid(NTOT / 128, GAL / 128);
    gemm_kernel<1><<<grid, 256, 0, stream>>>(bf, ws, ws);
    pos_kernel<<<GAL, 64, 0, stream>>>(bf, ws);
    gemm_kernel<2><<<grid, 256, 0, stream>>>(bf, ws, ws);
    finish_kernel<<<1, 1024, 0, stream>>>(ws, out);
}